// Round 1
// baseline (185.959 us; speedup 1.0000x reference)
//
#include <hip/hip_runtime.h>

// NormEMAVectorQuantizer on MI355X (gfx950)
// N=8192 tokens, C=32, K=8192 codes, B=32, H*W=256.
// R18 = R17 minus the second dense MFMA sweep:
//  k_sweep (was k_max) re-runs the 64 LDS-resident MFMAs per wave against the
//  per-chunk threshold chunkmax-eps and harvests candidate code ids (<=4 per
//  token,chunk; count byte; overflow -> dense fp32 fallback in k_pick2).
//  Certificate unchanged: bf16 dot err <= 2*2^-9 = 0.0078 < eps=0.01 and
//  chunkmax <= gmax, so the per-chunk candidate set is a superset of the
//  global candidate set {d >= gmax-eps}; every code that can be the fp32
//  argmax (incl. all ties) is exact-rescored in fp32 by k_pick2.
//  k_pick2 (32 blocks): per token: gmax over 32 chunk maxima, filter chunks
//  >= gmax-eps (~1.2), exact fp32 rescore ~1.6 candidates, explicit
//  (s, lowest-code) tie-break, write ids[] + out ids. packed u64 + its
//  zeroing + all global atomics deleted.
//
// Outputs (float32, concatenated):
//   [0 .. 262144)        z_q_out [B,C,H,W]
//   [262144]             loss (scalar)
//   [262145 .. 270337)   token_ids [B,H,W] as float
//   [270337 .. 532481)   new_embedding [K,C]
//   [532481 .. 540673)   new_cluster_sizes [K]

#define NTOK   8192
#define NCODE  8192
#define CDIM   32
#define HW     256
#define DECAYF 0.99f
#define EPSF   0.01f

#define OUT_ZQ   0
#define OUT_LOSS 262144
#define OUT_IDS  262145
#define OUT_EMB  270337
#define OUT_CS   532481

// workspace byte offsets
#define WS_ZN     0u        // f32 [N,C]                = 1048576
#define WS_ZNBF   1048576u  // bf16 [N,C]               = 524288
#define WS_EBF    1572864u  // bf16 [K,C]               = 524288
#define WS_PMAX   2097152u  // f32 [32][N]              = 1048576
#define WS_CCNT   3145728u  // u8  [32][N]              = 262144
#define WS_CAND   3407872u  // u16 [32][N][4]           = 2097152
#define WS_IDS    5505024u  // u32 [N]                  = 32768   (end 5537792)

#define CHUNK  256
#define NCHUNK (NCODE / CHUNK)  // 32
#define TILES  (CHUNK / 16)     // 16
#define CANDS  4

typedef __attribute__((ext_vector_type(8))) short bf16x8;
typedef __attribute__((ext_vector_type(4))) float f32x4;

__device__ inline unsigned short f2bf(float x) {
    unsigned u = __float_as_uint(x);
    return (unsigned short)((u + 0x7FFFu + ((u >> 16) & 1u)) >> 16);
}

// stage one 256x32 bf16 chunk into LDS with rows padded to 5 float4 units
// (80B): banks cycle 20*row%32 -> max 2-way conflict on read and write.
__device__ inline void stage_chunk(const unsigned short* __restrict__ ebf,
                                   int kbase, float4* lbs5, int t) {
    const float4* src = (const float4*)(ebf + (size_t)kbase * CDIM);
#pragma unroll
    for (int j = 0; j < 4; ++j) {
        int u = t + j * 256;                      // global float4 unit in chunk
        int row = u >> 2, seg = u & 3;
        lbs5[row * 5 + seg] = src[u];
    }
}

// exact fp32 dot, arithmetic identical to R17's rescore (proven vs reference)
__device__ __forceinline__ float dot32(const float* zr, const float* __restrict__ emb,
                                       int code) {
    const float4* ep4 = (const float4*)(emb + (size_t)code * CDIM);
    float a0 = 0.f, a1 = 0.f, a2 = 0.f, a3 = 0.f;
#pragma unroll
    for (int j = 0; j < 8; ++j) {
        float4 e4 = ep4[j];
        a0 = __builtin_fmaf(zr[4 * j + 0], e4.x, a0);
        a1 = __builtin_fmaf(zr[4 * j + 1], e4.y, a1);
        a2 = __builtin_fmaf(zr[4 * j + 2], e4.z, a2);
        a3 = __builtin_fmaf(zr[4 * j + 3], e4.w, a3);
    }
    return (a0 + a1) + (a2 + a3);
}

// -------- Kernel A: prep (norm + bf16 + emb bf16) + zero loss ------------------
__global__ __launch_bounds__(256) void k_prep(const float* __restrict__ z,
                                              const float* __restrict__ emb,
                                              float* __restrict__ zn,
                                              unsigned short* __restrict__ znbf,
                                              unsigned short* __restrict__ ebf,
                                              float* __restrict__ out) {
    int bid = blockIdx.x, t = threadIdx.x;
    if (bid < 32) {                               // token norm -> zn, znbf
        int n = bid * 256 + t;
        int b = n >> 8, hw = n & 255;
        const float* zp = z + (size_t)b * (CDIM * HW) + hw;
        float v[CDIM];
        float ss = 0.f;
#pragma unroll
        for (int c = 0; c < CDIM; ++c) {
            float tv = zp[c * HW];                // coalesced per c
            v[c] = tv;
            ss += tv * tv;
        }
        float d = fmaxf(sqrtf(ss), 1e-12f);
        float* o = zn + (size_t)n * CDIM;
        unsigned short* ob = znbf + (size_t)n * CDIM;
#pragma unroll
        for (int c = 0; c < CDIM; ++c) {
            float tv = v[c] / d;
            o[c] = tv;
            ob[c] = f2bf(tv);
        }
    } else if (bid < 160) {                       // emb -> ebf
        int base = (bid - 32) * 2048 + t * 8;
        const float4* s = (const float4*)(emb + base);
        float4 x4 = s[0], y4 = s[1];
        ushort4 u0 = {f2bf(x4.x), f2bf(x4.y), f2bf(x4.z), f2bf(x4.w)};
        ushort4 u1 = {f2bf(y4.x), f2bf(y4.y), f2bf(y4.z), f2bf(y4.w)};
        *(ushort4*)(ebf + base) = u0;
        *(ushort4*)(ebf + base + 4) = u1;
    } else {                                      // bid==160: zero loss slot
        if (t == 0) out[OUT_LOSS] = 0.f;
    }
}

// -------- Kernel B: single MFMA sweep: pmax + candidate harvest ----------------
__global__ __launch_bounds__(256) void k_sweep(const unsigned short* __restrict__ znbf,
                                               const unsigned short* __restrict__ ebf,
                                               float* __restrict__ pmax,
                                               unsigned char* __restrict__ ccnt,
                                               unsigned short* __restrict__ cand) {
    __shared__ float4 lbs5[CHUNK * 5];            // 20 KiB, 80B rows
    __shared__ float lmax[256];
    __shared__ int lcnt[256];
    int kbase = blockIdx.y * CHUNK;
    lcnt[threadIdx.x] = 0;
    stage_chunk(ebf, kbase, lbs5, threadIdx.x);
    __syncthreads();

    int wave = threadIdx.x >> 6, lane = threadIdx.x & 63;
    int col = lane & 15, quad = lane >> 4;
    int wtok = blockIdx.x * 256 + wave * 64;

    bf16x8 a[4];                                  // 4 frags = 64 tokens
#pragma unroll
    for (int f = 0; f < 4; ++f)
        a[f] = *(const bf16x8*)(znbf + (size_t)(wtok + f * 16 + col) * CDIM + quad * 8);

    const bf16x8* bl = (const bf16x8*)lbs5;       // 16B units, row stride 5
    const f32x4 zero4 = {0.f, 0.f, 0.f, 0.f};
    float m[4][4];
#pragma unroll
    for (int f = 0; f < 4; ++f)
#pragma unroll
        for (int r = 0; r < 4; ++r) m[f][r] = -1e30f;

    // ---- pass A: chunk max per token ----
    for (int t = 0; t < TILES; ++t) {
        bf16x8 b = bl[(t * 16 + col) * 5 + quad];
#pragma unroll
        for (int f = 0; f < 4; ++f) {
            f32x4 d = __builtin_amdgcn_mfma_f32_16x16x32_bf16(a[f], b, zero4, 0, 0, 0);
#pragma unroll
            for (int r = 0; r < 4; ++r) m[f][r] = fmaxf(m[f][r], d[r]);
        }
    }
    // cross-col reduce: all 16 lanes converge to the chunk max; store pmax,
    // keep thr = chunkmax - eps in m[][] for the harvest pass.
#pragma unroll
    for (int f = 0; f < 4; ++f)
#pragma unroll
        for (int r = 0; r < 4; ++r) {
            float v = m[f][r];
#pragma unroll
            for (int s = 1; s < 16; s <<= 1) v = fmaxf(v, __shfl_xor(v, s));
            if (col == 0) lmax[wave * 64 + f * 16 + quad * 4 + r] = v;
            m[f][r] = v - EPSF;
        }

    // ---- pass A': re-MFMA from LDS, harvest codes with d >= chunkmax - eps ----
    for (int t = 0; t < TILES; ++t) {
        bf16x8 b = bl[(t * 16 + col) * 5 + quad];
#pragma unroll
        for (int f = 0; f < 4; ++f) {
            f32x4 d = __builtin_amdgcn_mfma_f32_16x16x32_bf16(a[f], b, zero4, 0, 0, 0);
#pragma unroll
            for (int r = 0; r < 4; ++r) {
                if (d[r] >= m[f][r]) {            // ~1.05 per (token,chunk)
                    int ltok = wave * 64 + f * 16 + quad * 4 + r;
                    int slot = atomicAdd(&lcnt[ltok], 1);
                    if (slot < CANDS)
                        cand[((size_t)blockIdx.y * NTOK + blockIdx.x * 256 + ltok) * CANDS + slot] =
                            (unsigned short)(kbase + t * 16 + col);
                }
            }
        }
    }
    __syncthreads();
    size_t o = (size_t)blockIdx.y * NTOK + blockIdx.x * 256 + threadIdx.x;
    pmax[o] = lmax[threadIdx.x];
    int c = lcnt[threadIdx.x];
    ccnt[o] = (unsigned char)(c > 255 ? 255 : c);
}

// -------- Kernel C: tiny per-token gather + exact fp32 rescore -----------------
__global__ __launch_bounds__(256) void k_pick2(const float* __restrict__ zn,
                                               const float* __restrict__ emb,
                                               const float* __restrict__ pmax,
                                               const unsigned char* __restrict__ ccnt,
                                               const unsigned long long* __restrict__ cand64,
                                               unsigned int* __restrict__ ids,
                                               float* __restrict__ out) {
    int n = blockIdx.x * 256 + threadIdx.x;

    float pm[NCHUNK];
    float mx = -1e30f;
#pragma unroll
    for (int ch = 0; ch < NCHUNK; ++ch) {         // coalesced per chunk
        pm[ch] = pmax[(size_t)ch * NTOK + n];
        mx = fmaxf(mx, pm[ch]);
    }
    float thr = mx - EPSF;

    float zr[CDIM];                               // token row in regs
    const float4* zp4 = (const float4*)(zn + (size_t)n * CDIM);
#pragma unroll
    for (int j = 0; j < 8; ++j) {
        float4 v4 = zp4[j];
        zr[4 * j + 0] = v4.x;
        zr[4 * j + 1] = v4.y;
        zr[4 * j + 2] = v4.z;
        zr[4 * j + 3] = v4.w;
    }

    float best = -2e30f;
    int bcode = NCODE;
#pragma unroll 1
    for (int ch = 0; ch < NCHUNK; ++ch) {
        if (pm[ch] < thr) continue;               // ~1.2 chunks pass per token
        int cnt = ccnt[(size_t)ch * NTOK + n];
        if (cnt <= CANDS) {
            unsigned long long cw = cand64[(size_t)ch * NTOK + n];
            for (int s = 0; s < cnt; ++s) {
                int code = (int)((cw >> (16 * s)) & 0xFFFFu);
                float sc = dot32(zr, emb, code);
                if (sc > best || (sc == best && code < bcode)) { best = sc; bcode = code; }
            }
        } else {                                  // overflow: exact dense chunk
            for (int c = 0; c < CHUNK; ++c) {
                int code = ch * CHUNK + c;
                float sc = dot32(zr, emb, code);
                if (sc > best || (sc == best && code < bcode)) { best = sc; bcode = code; }
            }
        }
    }
    ids[n] = (unsigned int)bcode;
    out[OUT_IDS + n] = (float)bcode;
}

// -------- Kernel D: fused epilogue, 256 blocks ---------------------------------
// Block b: (a) z_q/loss for tokens 32b..32b+31; (b) bins+esum for codes
// 32b..32b+31 by scanning all ids (coalesced, ~8 hits/wave), then EMA.
__global__ __launch_bounds__(256) void k_final(const unsigned int* __restrict__ ids,
                                               const float* __restrict__ zn,
                                               const float* __restrict__ emb,
                                               const float* __restrict__ cs,
                                               float* __restrict__ out) {
    __shared__ float lesum[32][32];               // 4 KiB
    __shared__ int lbins[32];
    __shared__ int lsid[32];
    __shared__ float ls4[4];

    int blk = blockIdx.x, t = threadIdx.x;
    int wave = t >> 6, lane = t & 63;
    int tok0 = blk * 32, kbase = blk * 32;

    if (t < 32) lbins[t] = 0;
#pragma unroll
    for (int i = 0; i < 4; ++i) {
        int idx = i * 256 + t;
        lesum[idx >> 5][idx & 31] = 0.f;
    }
    if (t < 32) lsid[t] = (int)ids[tok0 + t];
    __syncthreads();

    // ---- z_q gather + transpose-out + loss partial ----
    float s = 0.f;
#pragma unroll
    for (int i = 0; i < 4; ++i) {
        int idx = i * 256 + t;
        int tl = idx >> 5, c = idx & 31;
        int n = tok0 + tl;
        int id = lsid[tl];
        float ev = emb[(size_t)id * CDIM + c];    // <=32 rows, L1/L2
        float zv = zn[(size_t)n * CDIM + c];      // coalesced row reads
        int b = n >> 8, hw = n & 255;
        out[OUT_ZQ + ((size_t)b * CDIM + c) * HW + hw] = ev;
        float dd = ev - zv;
        s += dd * dd;
    }
#pragma unroll
    for (int off = 32; off > 0; off >>= 1) s += __shfl_down(s, off);
    if (lane == 0) ls4[wave] = s;
    __syncthreads();
    if (t == 0)
        atomicAdd(out + OUT_LOSS,
                  (ls4[0] + ls4[1] + ls4[2] + ls4[3]) * (1.0f / 262144.0f));

    // ---- bins + esum: scan all tokens for hits in our code window ----
    for (int i = 0; i < 32; ++i) {
        int n = i * 256 + t;                      // coalesced
        int id = (int)ids[n];
        unsigned kl = (unsigned)(id - kbase);
        if (kl < 32u) {                           // ~8 hits per wave total
            atomicAdd(&lbins[kl], 1);
            const float* zp = zn + (size_t)n * CDIM;
#pragma unroll
            for (int c = 0; c < CDIM; ++c)
                atomicAdd(&lesum[kl][c], zp[c]);
        }
    }
    __syncthreads();

    // ---- EMA update + renormalize for our 32 codes ----
#pragma unroll
    for (int i = 0; i < 4; ++i) {
        int idx = i * 256 + t;
        int kl = idx >> 5, c = idx & 31;
        int k = kbase + kl;
        int bi = lbins[kl];
        float bf = (float)bi;
        bool zero = (bi == 0);
        float tv = lesum[kl][c] / (zero ? 1.0f : bf);
        float ss = tv * tv;
#pragma unroll
        for (int sh = 1; sh < 32; sh <<= 1) ss += __shfl_xor(ss, sh);
        float d = fmaxf(sqrtf(ss), 1e-12f);
        float ew = emb[(size_t)k * CDIM + c];
        float en = zero ? ew : (tv / d);
        float w = ew * DECAYF + (1.0f - DECAYF) * en;
        float ss2 = w * w;
#pragma unroll
        for (int sh = 1; sh < 32; sh <<= 1) ss2 += __shfl_xor(ss2, sh);
        float d2 = fmaxf(sqrtf(ss2), 1e-12f);
        out[OUT_EMB + (size_t)k * CDIM + c] = w / d2;
        if (c == 0) out[OUT_CS + k] = cs[k] * DECAYF + (1.0f - DECAYF) * bf;
    }
}

extern "C" void kernel_launch(void* const* d_in, const int* in_sizes, int n_in,
                              void* d_out, int out_size, void* d_ws, size_t ws_size,
                              hipStream_t stream) {
    const float* z   = (const float*)d_in[0];   // [32,32,16,16]
    const float* emb = (const float*)d_in[1];   // [8192,32]
    const float* cs  = (const float*)d_in[2];   // [8192]
    float* out = (float*)d_out;
    char* ws = (char*)d_ws;

    float* zn                  = (float*)(ws + WS_ZN);
    unsigned short* znbf       = (unsigned short*)(ws + WS_ZNBF);
    unsigned short* ebf        = (unsigned short*)(ws + WS_EBF);
    float* pmax                = (float*)(ws + WS_PMAX);
    unsigned char* ccnt        = (unsigned char*)(ws + WS_CCNT);
    unsigned short* cand       = (unsigned short*)(ws + WS_CAND);
    unsigned int* ids          = (unsigned int*)(ws + WS_IDS);

    k_prep<<<dim3(161), 256, 0, stream>>>(z, emb, zn, znbf, ebf, out);
    k_sweep<<<dim3(NTOK / 256, NCHUNK), 256, 0, stream>>>(znbf, ebf, pmax, ccnt, cand);
    k_pick2<<<dim3(NTOK / 256), 256, 0, stream>>>(zn, emb, pmax, ccnt,
                                                  (const unsigned long long*)cand, ids, out);
    k_final<<<dim3(256), 256, 0, stream>>>(ids, zn, emb, cs, out);
}